// Round 7
// baseline (19886.630 us; speedup 1.0000x reference)
//
#include <hip/hip_runtime.h>
#include <math.h>

#define NN 4096
#define KK 8
#define DD 512
#define HH 512
#define NB 256
#define TPB 512
#define NXCD 8
#define MAXT 4096                 // max ticks (ASAP depth ~500 expected)
#define ENTCAP 40960              // sum(L_i) <= 36864 plus per-tick pad
#define ENCCAP 16384              // NN + per-tick pad
#define NNHH ((size_t)NN * HH)

typedef float v2f __attribute__((ext_vector_type(2)));

// ws layout (bytes)
#define OFF_CTRL 0                            // barrier lines (zeroed each launch)
#define OFF_HDR  8192                         // int nticks
#define OFF_TCNT (OFF_HDR + 256)              // int gcnt[MAXT]   entries per tick
#define OFF_TOFF (OFF_TCNT + 4 * MAXT)        // int goff[MAXT]   4-aligned offsets
#define OFF_TCUR (OFF_TOFF + 4 * MAXT)        // int gcur[MAXT]   scatter cursors
#define OFF_ECNT (OFF_TCUR + 4 * MAXT)        // int gecnt[MAXT]  enc nodes per tick
#define OFF_EOFF (OFF_ECNT + 4 * MAXT)        // int geoff[MAXT]
#define OFF_ECUR (OFF_EOFF + 4 * MAXT)        // int gecur[MAXT]
#define OFF_LIST (OFF_ECUR + 4 * MAXT)        // int list[ENTCAP]: i|q<<12|ll<<16|lr<<20
#define OFF_XL   (OFF_LIST + 4 * ENTCAP)      // int xl[ENTCAP]: x-source row (or -1)
#define OFF_XR   (OFF_XL + 4 * ENTCAP)        // int xr[ENTCAP]
#define OFF_ENC  (OFF_XR + 4 * ENTCAP)        // int enc[ENCCAP]: i|ll<<12|lr<<16
#define OFF_H    (OFF_ENC + 4 * ENCCAP)       // float hbuf[2][2][NN][HH]
#define OFF_C    (OFF_H + 4 * 2 * 2 * NN * HH)    // float cbuf[2][NN][HH]
#define WS_ZERO_BYTES 8192

// tanh(x) = 1 - 2/(exp(2x)+1)  — saturates correctly at +/-inf, ~1e-6 abs err
__device__ __forceinline__ float fast_tanh2x(float two_x) {
    return 1.0f - 2.0f * __builtin_amdgcn_rcpf(__expf(two_x) + 1.0f);
}

// async global->LDS, 16B/lane — CACHED path (x0 immutable; ctx write-once:
// each ctx row is written exactly once via write-through store and only read
// at strictly later ticks; rows are 2KB-aligned; dispatch-start caches are
// clean -> a cached read can never observe a stale ctx line. R6-proven.)
__device__ __forceinline__ void glds16(const float* g, float* l) {
    typedef __attribute__((address_space(1))) const void GV;
    typedef __attribute__((address_space(3))) void LV;
    __builtin_amdgcn_global_load_lds((GV*)g, (LV*)l, 16, 0, 0);
}

// ---------------------------------------------------------------------------
// Memory model (R4/R5/R6-proven), R7 change: c joins h on the coherent pair.
//   h, c, ctx: agent-relaxed atomic STORE (write-through, MALL-visible once
//     vmcnt drains at the pre-barrier __syncthreads) + agent-relaxed atomic
//     LOAD (bypasses stale L1/L2). No fences anywhere.
//   (c must be coherent now: under ASAP ticks a node's list position — and
//    hence its p-slot/CU — changes between substeps.)
//   x0, ctx(read), list/xl/xr/enc, weights: plain cached loads, stay hot.
// ---------------------------------------------------------------------------
__device__ __forceinline__ void coh_store(float* p, float v) {
    __hip_atomic_store(p, v, __ATOMIC_RELAXED, __HIP_MEMORY_SCOPE_AGENT);
}
__device__ __forceinline__ v2f ldb2(const float* p) {
    unsigned long long raw = __hip_atomic_load((const unsigned long long*)p,
                                               __ATOMIC_RELAXED, __HIP_MEMORY_SCOPE_AGENT);
    union { unsigned long long u; v2f f; } c; c.u = raw; return c.f;
}
__device__ __forceinline__ float ld4(const float* p) {
    unsigned raw = __hip_atomic_load((const unsigned*)p,
                                     __ATOMIC_RELAXED, __HIP_MEMORY_SCOPE_AGENT);
    union { unsigned u; float f; } c; c.u = raw; return c.f;
}

// ---------------------------------------------------------------------------
// Prologue (single block): ASAP tick schedule.
//   L_i = max(ll,lr); start[i] = 0 for leaves, else max_c(start[c]+L_c+1).
//   Node i contributes entries (i,q) at tick start+q for q in [0,L) and an
//   enc entry at tick start+L. Parent constraint start_p >= start_c+L_c+1
//   guarantees parents read ctx strictly after the enc tick's barrier.
// ---------------------------------------------------------------------------
__global__ void __launch_bounds__(1024)
sched_kernel(const int* __restrict__ lch, const int* __restrict__ rch, char* ws) {
    const int t = threadIdx.x;
    int* hdr   = (int*)(ws + OFF_HDR);
    int* gcnt  = (int*)(ws + OFF_TCNT);
    int* goff  = (int*)(ws + OFF_TOFF);
    int* gcur  = (int*)(ws + OFF_TCUR);
    int* gecnt = (int*)(ws + OFF_ECNT);
    int* geoff = (int*)(ws + OFF_EOFF);
    int* gecur = (int*)(ws + OFF_ECUR);
    int* list  = (int*)(ws + OFF_LIST);
    int* xl    = (int*)(ws + OFF_XL);
    int* xr    = (int*)(ws + OFF_XR);
    int* enc   = (int*)(ws + OFF_ENC);

    __shared__ int s_meta[NN];     // ll | lr<<4 | L<<8
    __shared__ int s_start[NN];
    __shared__ int s_seg[1024];
    __shared__ int s_un, s_nt;

    for (int j = t; j < MAXT; j += 1024) { gcnt[j] = 0; gcur[j] = 0; gecnt[j] = 0; gecur[j] = 0; }
    if (t == 0) s_nt = 0;
    for (int i = t; i < NN; i += 1024) {
        int ll = 1, lr = 1; bool has = false;
#pragma unroll
        for (int k = 0; k < KK; ++k) {
            if (lch[i * KK + k] >= 0) { ll = k + 2; has = true; }
            if (rch[i * KK + k] >= 0) { lr = k + 2; has = true; }
        }
        const int L = ll > lr ? ll : lr;
        s_meta[i]  = ll | (lr << 4) | (L << 8);
        s_start[i] = has ? -1 : 0;
    }
    __syncthreads();

    // fixpoint on start[]; converges in depth iterations
    for (;;) {
        if (t == 0) s_un = 0;
        __syncthreads();
        int myUn = 0;
        for (int i = t; i < NN; i += 1024) {
            if (s_start[i] < 0) {
                int mx = 0; bool ok = true;
#pragma unroll
                for (int k = 0; k < KK; ++k) {
                    int c = lch[i * KK + k];
                    if (c >= 0) {
                        const int st = s_start[c];
                        if (st < 0) ok = false;
                        else { const int v = st + ((s_meta[c] >> 8) & 0xF) + 1; if (v > mx) mx = v; }
                    }
                    c = rch[i * KK + k];
                    if (c >= 0) {
                        const int st = s_start[c];
                        if (st < 0) ok = false;
                        else { const int v = st + ((s_meta[c] >> 8) & 0xF) + 1; if (v > mx) mx = v; }
                    }
                }
                if (ok) s_start[i] = mx; else ++myUn;
            }
        }
        if (myUn) atomicAdd(&s_un, myUn);
        __syncthreads();
        if (s_un == 0) break;
        __syncthreads();
    }

    // nticks = max(start+L)+1 ; histogram entries + enc per tick
    for (int i = t; i < NN; i += 1024)
        atomicMax(&s_nt, s_start[i] + ((s_meta[i] >> 8) & 0xF) + 1);
    __syncthreads();
    const int nt = s_nt;
    if (t == 0) hdr[0] = nt;
    for (int i = t; i < NN; i += 1024) {
        const int s = s_start[i], L = (s_meta[i] >> 8) & 0xF;
        for (int q = 0; q < L; ++q) atomicAdd(&gcnt[s + q], 1);
        atomicAdd(&gecnt[s + L], 1);
    }
    __syncthreads();

    // two-level prefix scan with 4-alignment: cnt -> off  (then enc likewise)
    auto scan4 = [&](int* cnt, int* off) {
        const int per = (nt + 1023) >> 10;
        const int lo = t * per, hi = (lo + per < nt) ? lo + per : nt;
        int sum = 0;
        for (int j = lo; j < hi; ++j) sum += (cnt[j] + 3) & ~3;
        s_seg[t] = sum;
        __syncthreads();
        if (t == 0) { int run = 0; for (int k = 0; k < 1024; ++k) { const int v = s_seg[k]; s_seg[k] = run; run += v; } }
        __syncthreads();
        int run = s_seg[t];
        for (int j = lo; j < hi; ++j) { off[j] = run; run += (cnt[j] + 3) & ~3; }
        __syncthreads();
    };
    scan4(gcnt, goff);
    scan4(gecnt, geoff);

    // scatter entries + enc nodes
    for (int i = t; i < NN; i += 1024) {
        const int m = s_meta[i], s = s_start[i];
        const int ll = m & 0xF, lr = (m >> 4) & 0xF, L = (m >> 8) & 0xF;
        for (int q = 0; q < L; ++q) {
            const int pos = goff[s + q] + atomicAdd(&gcur[s + q], 1);
            list[pos] = i | (q << 12) | (ll << 16) | (lr << 20);
            xl[pos] = (q == 0) ? i : ((q < ll) ? lch[i * KK + q - 1] : -1);
            xr[pos] = (q == 0) ? i : ((q < lr) ? rch[i * KK + q - 1] : -1);
        }
        const int ep = geoff[s + L] + atomicAdd(&gecur[s + L], 1);
        enc[ep] = i | (ll << 12) | (lr << 16);
    }
}

// ---------------------------------------------------------------------------
// Grid barrier (R4/R6-proven): leader-gather + XCD-fanout, flags only,
// relaxed agent scope, no fences, poll backoff. SAFE ONLY at <=256 blocks,
// 1 block/CU (enforced via the 84KB LDS pad).
// ---------------------------------------------------------------------------
__device__ __forceinline__ void grid_barrier(int* ctrl, int blk, int xcd, int target) {
    __syncthreads();   // every wave: s_waitcnt vmcnt(0) before s_barrier
    if (blk == 0) {
        const int t = threadIdx.x;
        if (t < 64) {
            if (t == 0)
                __hip_atomic_store(ctrl + 0, target, __ATOMIC_RELAXED, __HIP_MEMORY_SCOPE_AGENT);
            int spin = 0;
            for (;;) {
                const int m0 = __hip_atomic_load(ctrl + t * 4 + 0, __ATOMIC_RELAXED, __HIP_MEMORY_SCOPE_AGENT);
                const int m1 = __hip_atomic_load(ctrl + t * 4 + 1, __ATOMIC_RELAXED, __HIP_MEMORY_SCOPE_AGENT);
                const int m2 = __hip_atomic_load(ctrl + t * 4 + 2, __ATOMIC_RELAXED, __HIP_MEMORY_SCOPE_AGENT);
                const int m3 = __hip_atomic_load(ctrl + t * 4 + 3, __ATOMIC_RELAXED, __HIP_MEMORY_SCOPE_AGENT);
                const bool ok = (m0 >= target) & (m1 >= target) & (m2 >= target) & (m3 >= target);
                if (__all(ok)) break;
                if (++spin > 64) __builtin_amdgcn_s_sleep(16);
                else             __builtin_amdgcn_s_sleep(1);
            }
            if (t < NXCD)
                __hip_atomic_store(ctrl + 512 + t * 16, target, __ATOMIC_RELAXED, __HIP_MEMORY_SCOPE_AGENT);
        }
    } else {
        if (threadIdx.x == 0) {
            __hip_atomic_store(ctrl + blk, target, __ATOMIC_RELAXED, __HIP_MEMORY_SCOPE_AGENT);
            int spin = 0;
            while (__hip_atomic_load(ctrl + 512 + xcd * 16, __ATOMIC_RELAXED, __HIP_MEMORY_SCOPE_AGENT) < target) {
                if (++spin > 64) __builtin_amdgcn_s_sleep(16);
                else             __builtin_amdgcn_s_sleep(1);
            }
        }
    }
    __syncthreads();
}

// REGISTER ENVELOPE LAW (r3, r9): TPB=512 + __launch_bounds__(512,2) is the
// ONLY proven config keeping the weight hoist in registers. DO NOT TOUCH.
// Compute body = R6's proven form, re-indexed by per-entry (i,q,ll,lr).
__global__ void __launch_bounds__(TPB, 2)
tree_lstm_kernel(const float* __restrict__ x0,
                 const float* __restrict__ Wl_ih, const float* __restrict__ Wl_hh,
                 const float* __restrict__ bl_ih, const float* __restrict__ bl_hh,
                 const float* __restrict__ Wr_ih, const float* __restrict__ Wr_hh,
                 const float* __restrict__ br_ih, const float* __restrict__ br_hh,
                 const float* __restrict__ W_enc, const float* __restrict__ b_enc,
                 float* ctx, char* ws) {
    const int tid  = threadIdx.x;
    const int wv   = tid >> 6;                 // wave index within block, 0..7
    const int wave = (blockIdx.x * TPB + tid) >> 6;  // 0..2047
    const int lane = tid & 63;
    const int u    = wave & 511;       // hidden unit owned by this wave
    const int side = (wave >> 9) & 1;  // 0 = left chain, 1 = right chain
    const int p    = wave >> 10;       // 2-way slot split (uniform per block)
    const int egrp = wave >> 9;        // enc: 4-way slot split
    const int xcd  = blockIdx.x & (NXCD - 1);

    int*   ctrl  = (int*)(ws + OFF_CTRL);
    int*   hdr   = (int*)(ws + OFF_HDR);
    int*   gcnt  = (int*)(ws + OFF_TCNT);
    int*   goff  = (int*)(ws + OFF_TOFF);
    int*   gecnt = (int*)(ws + OFF_ECNT);
    int*   geoff = (int*)(ws + OFF_EOFF);
    int*   list  = (int*)(ws + OFF_LIST);
    int*   xlidx = (int*)(ws + OFF_XL);
    int*   xridx = (int*)(ws + OFF_XR);
    int*   encl  = (int*)(ws + OFF_ENC);
    float* hbuf  = (float*)(ws + OFF_H);
    float* cbuf  = (float*)(ws + OFF_C);

    // double-buffered row staging (x cached->LDS, h bypass->reg->LDS) + pad
    __shared__ float s_x[2][8][512];
    __shared__ float s_h[2][8][512];
    __shared__ float s_pad[5120];   // -> 84KB total: 1 block/CU

    const float* Wih = side ? Wr_ih : Wl_ih;
    const float* Whh = side ? Wr_hh : Wl_hh;
    const float* bih = side ? br_ih : bl_ih;
    const float* bhh = side ? br_hh : bl_hh;

    // Wave-resident weights: 4 gate rows; lane l covers dims {4l..4l+3} and
    // {256+4l..256+4l+3} (dense 16B slices matching the LDS staging layout).
    v2f wih2[4][4], whh2[4][4];
#pragma unroll
    for (int g = 0; g < 4; ++g) {
        const size_t row = (size_t)g * HH + u;
        const float4 wa = *(const float4*)(Wih + row * DD + lane * 4);
        const float4 wb = *(const float4*)(Wih + row * DD + 256 + lane * 4);
        wih2[g][0] = (v2f){wa.x, wa.y}; wih2[g][1] = (v2f){wa.z, wa.w};
        wih2[g][2] = (v2f){wb.x, wb.y}; wih2[g][3] = (v2f){wb.z, wb.w};
        const float4 ha = *(const float4*)(Whh + row * HH + lane * 4);
        const float4 hb = *(const float4*)(Whh + row * HH + 256 + lane * 4);
        whh2[g][0] = (v2f){ha.x, ha.y}; whh2[g][1] = (v2f){ha.z, ha.w};
        whh2[g][2] = (v2f){hb.x, hb.y}; whh2[g][3] = (v2f){hb.z, hb.w};
    }
    const float bsumL = bih[(size_t)(lane & 3) * HH + u] + bhh[(size_t)(lane & 3) * HH + u];
    v2f wenc2[8];
#pragma unroll
    for (int j = 0; j < 4; ++j) {
        const float4 t = *(const float4*)(W_enc + (size_t)u * (2 * HH) + lane * 16 + j * 4);
        wenc2[j * 2 + 0] = (v2f){t.x, t.y};
        wenc2[j * 2 + 1] = (v2f){t.z, t.w};
    }
    const float bencv = b_enc[u];

    float* cb = cbuf + (size_t)side * NNHH;
    const int* xq = side ? xridx : xlidx;
    const int nt = hdr[0];
    if (nt < 0) ((volatile float*)s_pad)[tid] = 0.f;  // keep pad alive
    int bnum = 0;

    for (int tk = 0; tk < nt; ++tk) {
        const int cnt  = gcnt[tk],  off  = goff[tk];
        const int ecnt = gecnt[tk], eoff = geoff[tk];
        const int limit = off + cnt;

        // slot p owns positions {slotBase + 16c + j, j in [0,8)}
        const int slotBase = off + p * 8;
        const int nch = (limit > slotBase) ? ((limit - slotBase + 15) >> 4) : 0;

        // staging: x rows cached glds16 -> LDS; h rows (per-entry parity)
        // ldb2 bypass -> regs (issue-early), ds_write after sync (write-late)
        v2f ph0, ph1, ph2, ph3;
        bool pact = false;

        auto issue = [&](int buf, int chS) {
            const int e = chS + wv;
            pact = false;
            if (e < limit) {
                const int ent  = list[e];
                const int q    = (ent >> 12) & 0xF;
                const int xsrc = xq[e];
                if (xsrc >= 0) {
                    const float* xrow = ((q == 0) ? x0 : ctx) + (size_t)xsrc * DD + lane * 4;
                    glds16(xrow,       &s_x[buf][wv][0]);
                    glds16(xrow + 256, &s_x[buf][wv][256]);
                    if (q > 0) {
                        pact = true;
                        const int i = ent & 0xFFF;
                        const float* hr = hbuf + (size_t)(((q & 1) ^ 1) * 2 + side) * NNHH
                                        + (size_t)i * HH + lane * 4;
                        ph0 = ldb2(hr);       ph1 = ldb2(hr + 2);
                        ph2 = ldb2(hr + 256); ph3 = ldb2(hr + 258);
                    }
                }
            }
        };
        auto writeb = [&](int buf) {
            if (pact) {
                *(v2f*)&s_h[buf][wv][lane * 4]       = ph0;
                *(v2f*)&s_h[buf][wv][lane * 4 + 2]   = ph1;
                *(v2f*)&s_h[buf][wv][lane * 4 + 256] = ph2;
                *(v2f*)&s_h[buf][wv][lane * 4 + 258] = ph3;
            }
        };

        if (nch > 0) { issue(0, slotBase); writeb(0); }
        for (int c = 0; c < nch; ++c) {
            __syncthreads();                    // buf[c&1] staged (all waves)
            const int chS = slotBase + (c << 4);
            if (c + 1 < nch) issue((c + 1) & 1, chS + 16);
            const int bb = c & 1;

            const int4 eA = *(const int4*)(list + chS);
            const int4 eB = *(const int4*)(list + chS + 4);
            const int4 cA = *(const int4*)(xq + chS);
            const int4 cB = *(const int4*)(xq + chS + 4);
            const int ei[8] = {eA.x, eA.y, eA.z, eA.w, eB.x, eB.y, eB.z, eB.w};
            const int ci[8] = {cA.x, cA.y, cA.z, cA.w, cB.x, cB.y, cB.z, cB.w};
            bool  act[8];
            float cp[8];
#pragma unroll
            for (int j = 0; j < 8; ++j)
                act[j] = (chS + j < limit) && (ci[j] >= 0);
#pragma unroll
            for (int j = 0; j < 8; ++j) {
                const int qj = (ei[j] >> 12) & 0xF;
                cp[j] = (act[j] && qj > 0) ? ld4(cb + (size_t)(ei[j] & 0xFFF) * HH + u) : 0.f;
            }

#pragma unroll
            for (int j = 0; j < 8; ++j) {
                if (!act[j]) continue;
                const int ent = ei[j];
                const int i   = ent & 0xFFF;
                const int qj  = (ent >> 12) & 0xF;
                const float4 xa = *(const float4*)&s_x[bb][j][lane * 4];
                const float4 xc = *(const float4*)&s_x[bb][j][lane * 4 + 256];
                v2f xv0 = (v2f){xa.x, xa.y}, xv1 = (v2f){xa.z, xa.w};
                v2f xv2 = (v2f){xc.x, xc.y}, xv3 = (v2f){xc.z, xc.w};
                v2f A0 = wih2[0][0] * xv0 + wih2[0][1] * xv1 + wih2[0][2] * xv2 + wih2[0][3] * xv3;
                v2f A1 = wih2[1][0] * xv0 + wih2[1][1] * xv1 + wih2[1][2] * xv2 + wih2[1][3] * xv3;
                v2f A2 = wih2[2][0] * xv0 + wih2[2][1] * xv1 + wih2[2][2] * xv2 + wih2[2][3] * xv3;
                v2f A3 = wih2[3][0] * xv0 + wih2[3][1] * xv1 + wih2[3][2] * xv2 + wih2[3][3] * xv3;
                if (qj > 0) {
                    const float4 ha = *(const float4*)&s_h[bb][j][lane * 4];
                    const float4 hc = *(const float4*)&s_h[bb][j][lane * 4 + 256];
                    v2f hv0 = (v2f){ha.x, ha.y}, hv1 = (v2f){ha.z, ha.w};
                    v2f hv2 = (v2f){hc.x, hc.y}, hv3 = (v2f){hc.z, hc.w};
                    A0 += whh2[0][0] * hv0 + whh2[0][1] * hv1 + whh2[0][2] * hv2 + whh2[0][3] * hv3;
                    A1 += whh2[1][0] * hv0 + whh2[1][1] * hv1 + whh2[1][2] * hv2 + whh2[1][3] * hv3;
                    A2 += whh2[2][0] * hv0 + whh2[2][1] * hv1 + whh2[2][2] * hv2 + whh2[2][3] * hv3;
                    A3 += whh2[3][0] * hv0 + whh2[3][1] * hv1 + whh2[3][2] * hv2 + whh2[3][3] * hv3;
                }
                float a0 = A0[0] + A0[1], a1 = A1[0] + A1[1];
                float a2 = A2[0] + A2[1], a3 = A3[0] + A3[1];
                // merge butterfly: lane l ends holding gate (l&3)'s sum
                float v01, v23, v;
                {
                    const bool hi = lane & 1;
                    float keep = hi ? a1 : a0, send = hi ? a0 : a1;
                    v01 = keep + __shfl_xor(send, 1, 64);
                    keep = hi ? a3 : a2; send = hi ? a2 : a3;
                    v23 = keep + __shfl_xor(send, 1, 64);
                }
                {
                    const bool hi = lane & 2;
                    const float keep = hi ? v23 : v01, send = hi ? v01 : v23;
                    v = keep + __shfl_xor(send, 2, 64);
                }
                v += __shfl_xor(v, 4, 64);
                v += __shfl_xor(v, 8, 64);
                v += __shfl_xor(v, 16, 64);
                v += __shfl_xor(v, 32, 64);
                // wave-parallel nonlinearities: sigm(x)=(tanh(x/2)+1)/2
                const float gate = v + bsumL;
                const bool  isG  = (lane & 3) == 2;
                const float th   = fast_tanh2x(isG ? (gate + gate) : gate);
                const float tl   = isG ? th : 0.5f * (th + 1.0f);
                const float ti = __shfl(tl, 0, 64);
                const float tf = __shfl(tl, 1, 64);
                const float tg = __shfl(tl, 2, 64);
                const float to = __shfl(tl, 3, 64);
                const float cn = tf * cp[j] + ti * tg;
                const float hn = to * fast_tanh2x(cn + cn);
                if (lane == 0) {
                    coh_store(cb + (size_t)i * HH + u, cn);
                    coh_store(hbuf + (size_t)((qj & 1) * 2 + side) * NNHH + (size_t)i * HH + u, hn);
                }
            }
            if (c + 1 < nch) writeb((c + 1) & 1);   // waits h loads, LDS write
        }

        // enc for nodes whose last substep ran at tick tk-1 (h MALL-visible)
        if (ecnt > 0) {
            const int lhalf = lane >> 5;
            const int col   = (lane * 16) & 511;
            const int elim  = eoff + ecnt;
            for (int slot = eoff + egrp; slot < elim; slot += 4) {
                const int e   = encl[slot];
                const int i   = e & 0xFFF;
                const int len = (e >> (12 + 4 * lhalf)) & 0xF;
                const float* hv = hbuf + (size_t)(((len - 1) & 1) * 2 + lhalf) * NNHH
                                + (size_t)i * HH + col;
                v2f acc2 = {0.f, 0.f};
#pragma unroll
                for (int k = 0; k < 8; ++k)
                    acc2 += wenc2[k] * ldb2(hv + k * 2);
                float acc = acc2[0] + acc2[1];
#pragma unroll
                for (int m = 1; m < 64; m <<= 1) acc += __shfl_xor(acc, m, 64);
                if (lane == 0)
                    coh_store(&ctx[(size_t)i * DD + u], fast_tanh2x(2.0f * (acc + bencv)));
            }
        }
        grid_barrier(ctrl, blockIdx.x, xcd, ++bnum);
    }
}

extern "C" void kernel_launch(void* const* d_in, const int* in_sizes, int n_in,
                              void* d_out, int out_size, void* d_ws, size_t ws_size,
                              hipStream_t stream) {
    hipMemsetAsync(d_ws, 0, WS_ZERO_BYTES, stream);
    sched_kernel<<<dim3(1), dim3(1024), 0, stream>>>(
        (const int*)d_in[11], (const int*)d_in[12], (char*)d_ws);
    tree_lstm_kernel<<<dim3(NB), dim3(TPB), 0, stream>>>(
        (const float*)d_in[0],
        (const float*)d_in[1], (const float*)d_in[2],
        (const float*)d_in[3], (const float*)d_in[4],
        (const float*)d_in[5], (const float*)d_in[6],
        (const float*)d_in[7], (const float*)d_in[8],
        (const float*)d_in[9], (const float*)d_in[10],
        (float*)d_out, (char*)d_ws);
}

// Round 8
// 15595.424 us; speedup vs baseline: 1.2752x; 1.2752x over previous
//
#include <hip/hip_runtime.h>
#include <math.h>

#define NN 4096
#define KK 8
#define DD 512
#define HH 512
#define NB 256
#define TPB 1024
#define NXCD 8
#define MAXT 4096                 // max ticks (ASAP depth ~500 expected)
#define ENTCAP 40960              // sum(L_i) <= 36864 plus per-tick pad
#define ENCCAP 16384              // NN + per-tick pad
#define NNHH ((size_t)NN * HH)

typedef float v2f __attribute__((ext_vector_type(2)));

// ws layout (bytes)
#define OFF_CTRL 0                            // barrier lines (zeroed each launch)
#define OFF_HDR  8192                         // int nticks
#define OFF_TCNT (OFF_HDR + 256)              // int gcnt[MAXT]   entries per tick
#define OFF_TOFF (OFF_TCNT + 4 * MAXT)        // int goff[MAXT]   4-aligned offsets
#define OFF_TCUR (OFF_TOFF + 4 * MAXT)        // int gcur[MAXT]   scatter cursors
#define OFF_ECNT (OFF_TCUR + 4 * MAXT)        // int gecnt[MAXT]  enc nodes per tick
#define OFF_EOFF (OFF_ECNT + 4 * MAXT)        // int geoff[MAXT]
#define OFF_ECUR (OFF_EOFF + 4 * MAXT)        // int gecur[MAXT]
#define OFF_LIST (OFF_ECUR + 4 * MAXT)        // int list[ENTCAP]: i|q<<12|ll<<16|lr<<20
#define OFF_XL   (OFF_LIST + 4 * ENTCAP)      // int xl[ENTCAP]: x-source row (or -1)
#define OFF_XR   (OFF_XL + 4 * ENTCAP)        // int xr[ENTCAP]
#define OFF_ENC  (OFF_XR + 4 * ENTCAP)        // int enc[ENCCAP]: i|ll<<12|lr<<16
#define OFF_H    (OFF_ENC + 4 * ENCCAP)       // float hbuf[2][2][NN][HH]
#define OFF_C    (OFF_H + 4 * 2 * 2 * NN * HH)    // float cbuf[2][NN][HH]
#define WS_ZERO_BYTES 8192

// tanh(x) = 1 - 2/(exp(2x)+1)  — saturates correctly at +/-inf, ~1e-6 abs err
__device__ __forceinline__ float fast_tanh2x(float two_x) {
    return 1.0f - 2.0f * __builtin_amdgcn_rcpf(__expf(two_x) + 1.0f);
}

// async global->LDS, 16B/lane — CACHED path (x0 immutable; ctx write-once:
// written exactly once via write-through store, read only at strictly later
// ticks, 2KB-aligned rows, dispatch-start caches clean. R6/R7-proven.)
__device__ __forceinline__ void glds16(const float* g, float* l) {
    typedef __attribute__((address_space(1))) const void GV;
    typedef __attribute__((address_space(3))) void LV;
    __builtin_amdgcn_global_load_lds((GV*)g, (LV*)l, 16, 0, 0);
}

// ---------------------------------------------------------------------------
// Memory model (R4..R7-proven):
//   h, c, ctx: agent-relaxed atomic STORE (write-through, MALL-visible once
//     vmcnt drains at the pre-barrier __syncthreads) + agent-relaxed atomic
//     LOAD (bypasses stale L1/L2). No fences anywhere.
//   x0, ctx(read), list/xl/xr/enc, weights: plain cached loads, stay hot.
// R8 CHANGE: cp (prev c) is no longer a per-wave uncached ld4 (that was an
//   ~800ns exposed MALL stall per chunk, consumed ~60ns after issue). The
//   block's 16 units are CONTIGUOUS (u0b..u0b+15), so each entry's c-segment
//   is one 64B span: staging lanes 0-7 prefetch it (latency-covered with the
//   h loads) and cp becomes a uniform LDS broadcast read.
// ---------------------------------------------------------------------------
__device__ __forceinline__ void coh_store(float* p, float v) {
    __hip_atomic_store(p, v, __ATOMIC_RELAXED, __HIP_MEMORY_SCOPE_AGENT);
}
__device__ __forceinline__ v2f ldb2(const float* p) {
    unsigned long long raw = __hip_atomic_load((const unsigned long long*)p,
                                               __ATOMIC_RELAXED, __HIP_MEMORY_SCOPE_AGENT);
    union { unsigned long long u; v2f f; } c; c.u = raw; return c.f;
}

// ---------------------------------------------------------------------------
// Prologue (single block): ASAP tick schedule. Verbatim from PASSING R7.
// ---------------------------------------------------------------------------
__global__ void __launch_bounds__(1024)
sched_kernel(const int* __restrict__ lch, const int* __restrict__ rch, char* ws) {
    const int t = threadIdx.x;
    int* hdr   = (int*)(ws + OFF_HDR);
    int* gcnt  = (int*)(ws + OFF_TCNT);
    int* goff  = (int*)(ws + OFF_TOFF);
    int* gcur  = (int*)(ws + OFF_TCUR);
    int* gecnt = (int*)(ws + OFF_ECNT);
    int* geoff = (int*)(ws + OFF_EOFF);
    int* gecur = (int*)(ws + OFF_ECUR);
    int* list  = (int*)(ws + OFF_LIST);
    int* xl    = (int*)(ws + OFF_XL);
    int* xr    = (int*)(ws + OFF_XR);
    int* enc   = (int*)(ws + OFF_ENC);

    __shared__ int s_meta[NN];     // ll | lr<<4 | L<<8
    __shared__ int s_start[NN];
    __shared__ int s_seg[1024];
    __shared__ int s_un, s_nt;

    for (int j = t; j < MAXT; j += 1024) { gcnt[j] = 0; gcur[j] = 0; gecnt[j] = 0; gecur[j] = 0; }
    if (t == 0) s_nt = 0;
    for (int i = t; i < NN; i += 1024) {
        int ll = 1, lr = 1; bool has = false;
#pragma unroll
        for (int k = 0; k < KK; ++k) {
            if (lch[i * KK + k] >= 0) { ll = k + 2; has = true; }
            if (rch[i * KK + k] >= 0) { lr = k + 2; has = true; }
        }
        const int L = ll > lr ? ll : lr;
        s_meta[i]  = ll | (lr << 4) | (L << 8);
        s_start[i] = has ? -1 : 0;
    }
    __syncthreads();

    // fixpoint on start[]; converges in depth iterations
    for (;;) {
        if (t == 0) s_un = 0;
        __syncthreads();
        int myUn = 0;
        for (int i = t; i < NN; i += 1024) {
            if (s_start[i] < 0) {
                int mx = 0; bool ok = true;
#pragma unroll
                for (int k = 0; k < KK; ++k) {
                    int c = lch[i * KK + k];
                    if (c >= 0) {
                        const int st = s_start[c];
                        if (st < 0) ok = false;
                        else { const int v = st + ((s_meta[c] >> 8) & 0xF) + 1; if (v > mx) mx = v; }
                    }
                    c = rch[i * KK + k];
                    if (c >= 0) {
                        const int st = s_start[c];
                        if (st < 0) ok = false;
                        else { const int v = st + ((s_meta[c] >> 8) & 0xF) + 1; if (v > mx) mx = v; }
                    }
                }
                if (ok) s_start[i] = mx; else ++myUn;
            }
        }
        if (myUn) atomicAdd(&s_un, myUn);
        __syncthreads();
        if (s_un == 0) break;
        __syncthreads();
    }

    for (int i = t; i < NN; i += 1024)
        atomicMax(&s_nt, s_start[i] + ((s_meta[i] >> 8) & 0xF) + 1);
    __syncthreads();
    const int nt = s_nt;
    if (t == 0) hdr[0] = nt;
    for (int i = t; i < NN; i += 1024) {
        const int s = s_start[i], L = (s_meta[i] >> 8) & 0xF;
        for (int q = 0; q < L; ++q) atomicAdd(&gcnt[s + q], 1);
        atomicAdd(&gecnt[s + L], 1);
    }
    __syncthreads();

    auto scan4 = [&](int* cnt, int* off) {
        const int per = (nt + 1023) >> 10;
        const int lo = t * per, hi = (lo + per < nt) ? lo + per : nt;
        int sum = 0;
        for (int j = lo; j < hi; ++j) sum += (cnt[j] + 3) & ~3;
        s_seg[t] = sum;
        __syncthreads();
        if (t == 0) { int run = 0; for (int k = 0; k < 1024; ++k) { const int v = s_seg[k]; s_seg[k] = run; run += v; } }
        __syncthreads();
        int run = s_seg[t];
        for (int j = lo; j < hi; ++j) { off[j] = run; run += (cnt[j] + 3) & ~3; }
        __syncthreads();
    };
    scan4(gcnt, goff);
    scan4(gecnt, geoff);

    for (int i = t; i < NN; i += 1024) {
        const int m = s_meta[i], s = s_start[i];
        const int ll = m & 0xF, lr = (m >> 4) & 0xF, L = (m >> 8) & 0xF;
        for (int q = 0; q < L; ++q) {
            const int pos = goff[s + q] + atomicAdd(&gcur[s + q], 1);
            list[pos] = i | (q << 12) | (ll << 16) | (lr << 20);
            xl[pos] = (q == 0) ? i : ((q < ll) ? lch[i * KK + q - 1] : -1);
            xr[pos] = (q == 0) ? i : ((q < lr) ? rch[i * KK + q - 1] : -1);
        }
        const int ep = geoff[s + L] + atomicAdd(&gecur[s + L], 1);
        enc[ep] = i | (ll << 12) | (lr << 16);
    }
}

// ---------------------------------------------------------------------------
// Grid barrier (R4/R6/R7-proven): leader-gather + XCD-fanout, flags only,
// relaxed agent scope, no fences, poll backoff. SAFE ONLY at <=256 blocks,
// 1 block/CU (TPB=1024 + 85KB LDS + VGPR make 1/CU unconditional).
// ---------------------------------------------------------------------------
__device__ __forceinline__ void grid_barrier(int* ctrl, int blk, int xcd, int target) {
    __syncthreads();   // every wave: s_waitcnt vmcnt(0) before s_barrier
    if (blk == 0) {
        const int t = threadIdx.x;
        if (t < 64) {
            if (t == 0)
                __hip_atomic_store(ctrl + 0, target, __ATOMIC_RELAXED, __HIP_MEMORY_SCOPE_AGENT);
            int spin = 0;
            for (;;) {
                const int m0 = __hip_atomic_load(ctrl + t * 4 + 0, __ATOMIC_RELAXED, __HIP_MEMORY_SCOPE_AGENT);
                const int m1 = __hip_atomic_load(ctrl + t * 4 + 1, __ATOMIC_RELAXED, __HIP_MEMORY_SCOPE_AGENT);
                const int m2 = __hip_atomic_load(ctrl + t * 4 + 2, __ATOMIC_RELAXED, __HIP_MEMORY_SCOPE_AGENT);
                const int m3 = __hip_atomic_load(ctrl + t * 4 + 3, __ATOMIC_RELAXED, __HIP_MEMORY_SCOPE_AGENT);
                const bool ok = (m0 >= target) & (m1 >= target) & (m2 >= target) & (m3 >= target);
                if (__all(ok)) break;
                if (++spin > 64) __builtin_amdgcn_s_sleep(16);
                else             __builtin_amdgcn_s_sleep(1);
            }
            if (t < NXCD)
                __hip_atomic_store(ctrl + 512 + t * 16, target, __ATOMIC_RELAXED, __HIP_MEMORY_SCOPE_AGENT);
        }
    } else {
        if (threadIdx.x == 0) {
            __hip_atomic_store(ctrl + blk, target, __ATOMIC_RELAXED, __HIP_MEMORY_SCOPE_AGENT);
            int spin = 0;
            while (__hip_atomic_load(ctrl + 512 + xcd * 16, __ATOMIC_RELAXED, __HIP_MEMORY_SCOPE_AGENT) < target) {
                if (++spin > 64) __builtin_amdgcn_s_sleep(16);
                else             __builtin_amdgcn_s_sleep(1);
            }
        }
    }
    __syncthreads();
}

// R8 OCCUPANCY EXPERIMENT: the R0-R7 invariance (17.2-17.5ms steady across
// four memory models and two schedules, VALUBusy ~26%) is a latency-hiding
// floor: TPB=512 + 1 block/CU = 2 waves/SIMD cannot hide ~900ns MALL latency
// under ~500ns of work. TPB=1024 + __launch_bounds__(1024,1) gives 4 waves/
// SIMD (cap 256 VGPR — we use ~110; the envelope law's failures were
// (1024,2)=64-cap and (512,4)=128-cap, NOT (1024,1)). Revert signature:
// VGPR_Count <= 64 or FETCH/WRITE explosion (scratch) or dur >> 17ms.
__global__ void __launch_bounds__(TPB, 1)
tree_lstm_kernel(const float* __restrict__ x0,
                 const float* __restrict__ Wl_ih, const float* __restrict__ Wl_hh,
                 const float* __restrict__ bl_ih, const float* __restrict__ bl_hh,
                 const float* __restrict__ Wr_ih, const float* __restrict__ Wr_hh,
                 const float* __restrict__ br_ih, const float* __restrict__ br_hh,
                 const float* __restrict__ W_enc, const float* __restrict__ b_enc,
                 float* ctx, char* ws) {
    const int tid  = threadIdx.x;
    const int wv   = tid >> 6;                 // wave index within block, 0..15
    const int wave = (blockIdx.x * TPB + tid) >> 6;  // 0..4095
    const int lane = tid & 63;
    const int u    = wave & 511;        // hidden unit owned by this wave
    const int side = (wave >> 9) & 1;   // 0 = left chain, 1 = right chain
    const int p    = (wave >> 10) & 3;  // 4-way slot split (uniform per block)
    const int egrp = (wave >> 9) & 7;   // enc: 8-way slot split
    const int xcd  = blockIdx.x & (NXCD - 1);
    const int u0b  = (blockIdx.x * 16) & 511;  // block's first unit (16 contiguous)

    int*   ctrl  = (int*)(ws + OFF_CTRL);
    int*   hdr   = (int*)(ws + OFF_HDR);
    int*   gcnt  = (int*)(ws + OFF_TCNT);
    int*   goff  = (int*)(ws + OFF_TOFF);
    int*   gecnt = (int*)(ws + OFF_ECNT);
    int*   geoff = (int*)(ws + OFF_EOFF);
    int*   list  = (int*)(ws + OFF_LIST);
    int*   xlidx = (int*)(ws + OFF_XL);
    int*   xridx = (int*)(ws + OFF_XR);
    int*   encl  = (int*)(ws + OFF_ENC);
    float* hbuf  = (float*)(ws + OFF_H);
    float* cbuf  = (float*)(ws + OFF_C);

    // double-buffered row staging (x cached->LDS, h/c bypass->reg->LDS) + pad
    __shared__ float s_x[2][8][512];
    __shared__ float s_h[2][8][512];
    __shared__ float s_c[2][8][16];
    __shared__ float s_pad[5120];   // -> ~85KB total: 1 block/CU guaranteed

    const float* Wih = side ? Wr_ih : Wl_ih;
    const float* Whh = side ? Wr_hh : Wl_hh;
    const float* bih = side ? br_ih : bl_ih;
    const float* bhh = side ? br_hh : bl_hh;

    // Wave-resident weights: 4 gate rows; lane l covers dims {4l..4l+3} and
    // {256+4l..256+4l+3} (dense 16B slices matching the LDS staging layout).
    v2f wih2[4][4], whh2[4][4];
#pragma unroll
    for (int g = 0; g < 4; ++g) {
        const size_t row = (size_t)g * HH + u;
        const float4 wa = *(const float4*)(Wih + row * DD + lane * 4);
        const float4 wb = *(const float4*)(Wih + row * DD + 256 + lane * 4);
        wih2[g][0] = (v2f){wa.x, wa.y}; wih2[g][1] = (v2f){wa.z, wa.w};
        wih2[g][2] = (v2f){wb.x, wb.y}; wih2[g][3] = (v2f){wb.z, wb.w};
        const float4 ha = *(const float4*)(Whh + row * HH + lane * 4);
        const float4 hb = *(const float4*)(Whh + row * HH + 256 + lane * 4);
        whh2[g][0] = (v2f){ha.x, ha.y}; whh2[g][1] = (v2f){ha.z, ha.w};
        whh2[g][2] = (v2f){hb.x, hb.y}; whh2[g][3] = (v2f){hb.z, hb.w};
    }
    const float bsumL = bih[(size_t)(lane & 3) * HH + u] + bhh[(size_t)(lane & 3) * HH + u];
    v2f wenc2[8];
#pragma unroll
    for (int j = 0; j < 4; ++j) {
        const float4 t = *(const float4*)(W_enc + (size_t)u * (2 * HH) + lane * 16 + j * 4);
        wenc2[j * 2 + 0] = (v2f){t.x, t.y};
        wenc2[j * 2 + 1] = (v2f){t.z, t.w};
    }
    const float bencv = b_enc[u];

    float* cb = cbuf + (size_t)side * NNHH;
    const int* xq = side ? xridx : xlidx;
    const int nt = hdr[0];
    if (nt < 0) ((volatile float*)s_pad)[tid] = 0.f;  // keep pad alive
    int bnum = 0;

    for (int tk = 0; tk < nt; ++tk) {
        const int cnt  = gcnt[tk],  off  = goff[tk];
        const int ecnt = gecnt[tk], eoff = geoff[tk];
        const int limit = off + cnt;

        // slot p owns positions {slotBase + 32c + j, j in [0,8)}
        const int slotBase = off + p * 8;
        const int nch = (limit > slotBase) ? ((limit - slotBase + 31) >> 5) : 0;

        // staging (waves 0-7 only): x rows cached glds16 -> LDS; h rows
        // ldb2 bypass -> regs; c-segment (block's 16 units, 64B) on lanes 0-7.
        // issue-early / write-late (ds_write after the next __syncthreads).
        v2f ph0, ph1, ph2, ph3, pc;
        bool pact = false;

        auto issue = [&](int buf, int chS) {
            pact = false;
            if (wv < 8) {
                const int e = chS + wv;
                if (e < limit) {
                    const int ent  = list[e];
                    const int q    = (ent >> 12) & 0xF;
                    const int xsrc = xq[e];
                    if (xsrc >= 0) {
                        const float* xrow = ((q == 0) ? x0 : ctx) + (size_t)xsrc * DD + lane * 4;
                        glds16(xrow,       &s_x[buf][wv][0]);
                        glds16(xrow + 256, &s_x[buf][wv][256]);
                        if (q > 0) {
                            pact = true;
                            const int i = ent & 0xFFF;
                            const float* hr = hbuf + (size_t)(((q & 1) ^ 1) * 2 + side) * NNHH
                                            + (size_t)i * HH + lane * 4;
                            ph0 = ldb2(hr);       ph1 = ldb2(hr + 2);
                            ph2 = ldb2(hr + 256); ph3 = ldb2(hr + 258);
                            if (lane < 8)
                                pc = ldb2(cb + (size_t)i * HH + u0b + lane * 2);
                        }
                    }
                }
            }
        };
        auto writeb = [&](int buf) {
            if (pact) {
                *(v2f*)&s_h[buf][wv][lane * 4]       = ph0;
                *(v2f*)&s_h[buf][wv][lane * 4 + 2]   = ph1;
                *(v2f*)&s_h[buf][wv][lane * 4 + 256] = ph2;
                *(v2f*)&s_h[buf][wv][lane * 4 + 258] = ph3;
                if (lane < 8)
                    *(v2f*)&s_c[buf][wv][lane * 2] = pc;
            }
        };

        if (nch > 0) { issue(0, slotBase); writeb(0); }
        for (int c = 0; c < nch; ++c) {
            __syncthreads();                    // buf[c&1] staged (all waves)
            const int chS = slotBase + (c << 5);
            if (c + 1 < nch) issue((c + 1) & 1, chS + 32);
            const int bb = c & 1;

            const int4 eA = *(const int4*)(list + chS);
            const int4 eB = *(const int4*)(list + chS + 4);
            const int4 cA = *(const int4*)(xq + chS);
            const int4 cB = *(const int4*)(xq + chS + 4);
            const int ei[8] = {eA.x, eA.y, eA.z, eA.w, eB.x, eB.y, eB.z, eB.w};
            const int ci[8] = {cA.x, cA.y, cA.z, cA.w, cB.x, cB.y, cB.z, cB.w};
            bool act[8];
#pragma unroll
            for (int j = 0; j < 8; ++j)
                act[j] = (chS + j < limit) && (ci[j] >= 0);

#pragma unroll
            for (int j = 0; j < 8; ++j) {
                if (!act[j]) continue;
                const int ent = ei[j];
                const int i   = ent & 0xFFF;
                const int qj  = (ent >> 12) & 0xF;
                const float cpj = (qj > 0) ? s_c[bb][j][wv] : 0.f;  // LDS broadcast
                const float4 xa = *(const float4*)&s_x[bb][j][lane * 4];
                const float4 xc = *(const float4*)&s_x[bb][j][lane * 4 + 256];
                v2f xv0 = (v2f){xa.x, xa.y}, xv1 = (v2f){xa.z, xa.w};
                v2f xv2 = (v2f){xc.x, xc.y}, xv3 = (v2f){xc.z, xc.w};
                v2f A0 = wih2[0][0] * xv0 + wih2[0][1] * xv1 + wih2[0][2] * xv2 + wih2[0][3] * xv3;
                v2f A1 = wih2[1][0] * xv0 + wih2[1][1] * xv1 + wih2[1][2] * xv2 + wih2[1][3] * xv3;
                v2f A2 = wih2[2][0] * xv0 + wih2[2][1] * xv1 + wih2[2][2] * xv2 + wih2[2][3] * xv3;
                v2f A3 = wih2[3][0] * xv0 + wih2[3][1] * xv1 + wih2[3][2] * xv2 + wih2[3][3] * xv3;
                if (qj > 0) {
                    const float4 ha = *(const float4*)&s_h[bb][j][lane * 4];
                    const float4 hc = *(const float4*)&s_h[bb][j][lane * 4 + 256];
                    v2f hv0 = (v2f){ha.x, ha.y}, hv1 = (v2f){ha.z, ha.w};
                    v2f hv2 = (v2f){hc.x, hc.y}, hv3 = (v2f){hc.z, hc.w};
                    A0 += whh2[0][0] * hv0 + whh2[0][1] * hv1 + whh2[0][2] * hv2 + whh2[0][3] * hv3;
                    A1 += whh2[1][0] * hv0 + whh2[1][1] * hv1 + whh2[1][2] * hv2 + whh2[1][3] * hv3;
                    A2 += whh2[2][0] * hv0 + whh2[2][1] * hv1 + whh2[2][2] * hv2 + whh2[2][3] * hv3;
                    A3 += whh2[3][0] * hv0 + whh2[3][1] * hv1 + whh2[3][2] * hv2 + whh2[3][3] * hv3;
                }
                float a0 = A0[0] + A0[1], a1 = A1[0] + A1[1];
                float a2 = A2[0] + A2[1], a3 = A3[0] + A3[1];
                // merge butterfly: lane l ends holding gate (l&3)'s sum
                float v01, v23, v;
                {
                    const bool hi = lane & 1;
                    float keep = hi ? a1 : a0, send = hi ? a0 : a1;
                    v01 = keep + __shfl_xor(send, 1, 64);
                    keep = hi ? a3 : a2; send = hi ? a2 : a3;
                    v23 = keep + __shfl_xor(send, 1, 64);
                }
                {
                    const bool hi = lane & 2;
                    const float keep = hi ? v23 : v01, send = hi ? v01 : v23;
                    v = keep + __shfl_xor(send, 2, 64);
                }
                v += __shfl_xor(v, 4, 64);
                v += __shfl_xor(v, 8, 64);
                v += __shfl_xor(v, 16, 64);
                v += __shfl_xor(v, 32, 64);
                // wave-parallel nonlinearities: sigm(x)=(tanh(x/2)+1)/2
                const float gate = v + bsumL;
                const bool  isG  = (lane & 3) == 2;
                const float th   = fast_tanh2x(isG ? (gate + gate) : gate);
                const float tl   = isG ? th : 0.5f * (th + 1.0f);
                const float ti = __shfl(tl, 0, 64);
                const float tf = __shfl(tl, 1, 64);
                const float tg = __shfl(tl, 2, 64);
                const float to = __shfl(tl, 3, 64);
                const float cn = tf * cpj + ti * tg;
                const float hn = to * fast_tanh2x(cn + cn);
                if (lane == 0) {
                    coh_store(cb + (size_t)i * HH + u, cn);
                    coh_store(hbuf + (size_t)((qj & 1) * 2 + side) * NNHH + (size_t)i * HH + u, hn);
                }
            }
            if (c + 1 < nch) writeb((c + 1) & 1);   // waits loads, LDS write
        }

        // enc for nodes whose last substep ran at tick tk-1 (h MALL-visible)
        if (ecnt > 0) {
            const int lhalf = lane >> 5;
            const int col   = (lane * 16) & 511;
            const int elim  = eoff + ecnt;
            for (int slot = eoff + egrp; slot < elim; slot += 8) {
                const int e   = encl[slot];
                const int i   = e & 0xFFF;
                const int len = (e >> (12 + 4 * lhalf)) & 0xF;
                const float* hv = hbuf + (size_t)(((len - 1) & 1) * 2 + lhalf) * NNHH
                                + (size_t)i * HH + col;
                v2f acc2 = {0.f, 0.f};
#pragma unroll
                for (int k = 0; k < 8; ++k)
                    acc2 += wenc2[k] * ldb2(hv + k * 2);
                float acc = acc2[0] + acc2[1];
#pragma unroll
                for (int m = 1; m < 64; m <<= 1) acc += __shfl_xor(acc, m, 64);
                if (lane == 0)
                    coh_store(&ctx[(size_t)i * DD + u], fast_tanh2x(2.0f * (acc + bencv)));
            }
        }
        grid_barrier(ctrl, blockIdx.x, xcd, ++bnum);
    }
}

extern "C" void kernel_launch(void* const* d_in, const int* in_sizes, int n_in,
                              void* d_out, int out_size, void* d_ws, size_t ws_size,
                              hipStream_t stream) {
    hipMemsetAsync(d_ws, 0, WS_ZERO_BYTES, stream);
    sched_kernel<<<dim3(1), dim3(1024), 0, stream>>>(
        (const int*)d_in[11], (const int*)d_in[12], (char*)d_ws);
    tree_lstm_kernel<<<dim3(NB), dim3(TPB), 0, stream>>>(
        (const float*)d_in[0],
        (const float*)d_in[1], (const float*)d_in[2],
        (const float*)d_in[3], (const float*)d_in[4],
        (const float*)d_in[5], (const float*)d_in[6],
        (const float*)d_in[7], (const float*)d_in[8],
        (const float*)d_in[9], (const float*)d_in[10],
        (float*)d_out, (char*)d_ws);
}

// Round 9
// 13663.713 us; speedup vs baseline: 1.4554x; 1.1414x over previous
//
#include <hip/hip_runtime.h>
#include <math.h>

#define NN 4096
#define KK 8
#define DD 512
#define HH 512
#define NB 256
#define TPB 1024
#define NXCD 8
#define MAXT 4096                 // max ticks
#define ENTCAP 40960              // sum(L_i) <= 36864 plus per-tick pad
#define ENCCAP 16384              // NN + per-tick pad
#define NNHH ((size_t)NN * HH)

typedef float v2f __attribute__((ext_vector_type(2)));

// ws layout (bytes)
#define OFF_CTRL 0                            // barrier lines (zeroed each launch)
#define OFF_HDR  8192                         // int nticks
#define OFF_TCNT (OFF_HDR + 256)              // int gcnt[MAXT]   entries per tick
#define OFF_TOFF (OFF_TCNT + 4 * MAXT)        // int goff[MAXT]   4-aligned offsets
#define OFF_TCUR (OFF_TOFF + 4 * MAXT)        // int gcur[MAXT]   scatter cursors
#define OFF_ECNT (OFF_TCUR + 4 * MAXT)        // int gecnt[MAXT]  enc nodes per tick
#define OFF_EOFF (OFF_ECNT + 4 * MAXT)        // int geoff[MAXT]
#define OFF_ECUR (OFF_EOFF + 4 * MAXT)        // int gecur[MAXT]
#define OFF_LIST (OFF_ECUR + 4 * MAXT)        // int list[ENTCAP]: i|q<<12|ll<<16|lr<<20
#define OFF_XL   (OFF_LIST + 4 * ENTCAP)      // int xl[ENTCAP]: x-source row (or -1)
#define OFF_XR   (OFF_XL + 4 * ENTCAP)        // int xr[ENTCAP]
#define OFF_ENC  (OFF_XR + 4 * ENTCAP)        // int enc[ENCCAP]: i|ll<<12|lr<<16
#define OFF_H    (OFF_ENC + 4 * ENCCAP)       // float hbuf[2][2][NN][HH]
#define OFF_C    (OFF_H + 4 * 2 * 2 * NN * HH)    // float cbuf[2][NN][HH]
#define WS_ZERO_BYTES 8192

// tanh(x) = 1 - 2/(exp(2x)+1)  — saturates correctly at +/-inf, ~1e-6 abs err
__device__ __forceinline__ float fast_tanh2x(float two_x) {
    return 1.0f - 2.0f * __builtin_amdgcn_rcpf(__expf(two_x) + 1.0f);
}

// async global->LDS, 16B/lane — CACHED path (x0 immutable; ctx write-once:
// written exactly once via write-through store, read only at strictly later
// ticks, 2KB-aligned rows, dispatch-start caches clean. R6/R7/R8-proven.)
__device__ __forceinline__ void glds16(const float* g, float* l) {
    typedef __attribute__((address_space(1))) const void GV;
    typedef __attribute__((address_space(3))) void LV;
    __builtin_amdgcn_global_load_lds((GV*)g, (LV*)l, 16, 0, 0);
}

// ---------------------------------------------------------------------------
// Memory model (R4..R8-proven):
//   h, c, ctx: agent-relaxed atomic STORE (write-through, MALL-visible once
//     vmcnt drains at the pre-barrier __syncthreads) + agent-relaxed atomic
//     LOAD (bypasses stale L1/L2). No fences anywhere.
//   x0, ctx(read), list/xl/xr/enc, weights: plain cached loads, stay hot.
//   cp (prev c) staged through LDS per block-contiguous 16-unit segment (R8).
// ---------------------------------------------------------------------------
__device__ __forceinline__ void coh_store(float* p, float v) {
    __hip_atomic_store(p, v, __ATOMIC_RELAXED, __HIP_MEMORY_SCOPE_AGENT);
}
__device__ __forceinline__ v2f ldb2(const float* p) {
    unsigned long long raw = __hip_atomic_load((const unsigned long long*)p,
                                               __ATOMIC_RELAXED, __HIP_MEMORY_SCOPE_AGENT);
    union { unsigned long long u; v2f f; } c; c.u = raw; return c.f;
}

// ---------------------------------------------------------------------------
// Prologue (single block): ASAP tick schedule.
// R9 CHANGE (the round's single edit): per-position read slack.
//   Parent's q=0 substep reads its OWN x0 (never ctx); the child at list
//   position k is first read at substep q=k+1, i.e., tick start_j + k + 1.
//   Visibility needs start_j + k + 1 >= enc_c + 1 = start_c + L_c + 1, so
//     start_j = max(0, max over child occurrences (c,k): start_c + L_c - k)
//   (was start_c + L_c + 1 for every child — up to k+1 ticks too strict).
//   Critical-path hops ~180, binding position avg ~1-3 -> expect 15-30%
//   fewer ticks. Everything downstream (hist/scan/scatter) unchanged.
// ---------------------------------------------------------------------------
__global__ void __launch_bounds__(1024)
sched_kernel(const int* __restrict__ lch, const int* __restrict__ rch, char* ws) {
    const int t = threadIdx.x;
    int* hdr   = (int*)(ws + OFF_HDR);
    int* gcnt  = (int*)(ws + OFF_TCNT);
    int* goff  = (int*)(ws + OFF_TOFF);
    int* gcur  = (int*)(ws + OFF_TCUR);
    int* gecnt = (int*)(ws + OFF_ECNT);
    int* geoff = (int*)(ws + OFF_EOFF);
    int* gecur = (int*)(ws + OFF_ECUR);
    int* list  = (int*)(ws + OFF_LIST);
    int* xl    = (int*)(ws + OFF_XL);
    int* xr    = (int*)(ws + OFF_XR);
    int* enc   = (int*)(ws + OFF_ENC);

    __shared__ int s_meta[NN];     // ll | lr<<4 | L<<8
    __shared__ int s_start[NN];
    __shared__ int s_seg[1024];
    __shared__ int s_un, s_nt;

    for (int j = t; j < MAXT; j += 1024) { gcnt[j] = 0; gcur[j] = 0; gecnt[j] = 0; gecur[j] = 0; }
    if (t == 0) s_nt = 0;
    for (int i = t; i < NN; i += 1024) {
        int ll = 1, lr = 1; bool has = false;
#pragma unroll
        for (int k = 0; k < KK; ++k) {
            if (lch[i * KK + k] >= 0) { ll = k + 2; has = true; }
            if (rch[i * KK + k] >= 0) { lr = k + 2; has = true; }
        }
        const int L = ll > lr ? ll : lr;
        s_meta[i]  = ll | (lr << 4) | (L << 8);
        s_start[i] = has ? -1 : 0;
    }
    __syncthreads();

    // fixpoint on start[]; converges in depth iterations
    for (;;) {
        if (t == 0) s_un = 0;
        __syncthreads();
        int myUn = 0;
        for (int i = t; i < NN; i += 1024) {
            if (s_start[i] < 0) {
                int mx = 0; bool ok = true;
#pragma unroll
                for (int k = 0; k < KK; ++k) {
                    int c = lch[i * KK + k];
                    if (c >= 0) {
                        const int st = s_start[c];
                        if (st < 0) ok = false;
                        else { const int v = st + ((s_meta[c] >> 8) & 0xF) - k; if (v > mx) mx = v; }
                    }
                    c = rch[i * KK + k];
                    if (c >= 0) {
                        const int st = s_start[c];
                        if (st < 0) ok = false;
                        else { const int v = st + ((s_meta[c] >> 8) & 0xF) - k; if (v > mx) mx = v; }
                    }
                }
                if (ok) s_start[i] = mx; else ++myUn;
            }
        }
        if (myUn) atomicAdd(&s_un, myUn);
        __syncthreads();
        if (s_un == 0) break;
        __syncthreads();
    }

    for (int i = t; i < NN; i += 1024)
        atomicMax(&s_nt, s_start[i] + ((s_meta[i] >> 8) & 0xF) + 1);
    __syncthreads();
    const int nt = s_nt;
    if (t == 0) hdr[0] = nt;
    for (int i = t; i < NN; i += 1024) {
        const int s = s_start[i], L = (s_meta[i] >> 8) & 0xF;
        for (int q = 0; q < L; ++q) atomicAdd(&gcnt[s + q], 1);
        atomicAdd(&gecnt[s + L], 1);
    }
    __syncthreads();

    auto scan4 = [&](int* cnt, int* off) {
        const int per = (nt + 1023) >> 10;
        const int lo = t * per, hi = (lo + per < nt) ? lo + per : nt;
        int sum = 0;
        for (int j = lo; j < hi; ++j) sum += (cnt[j] + 3) & ~3;
        s_seg[t] = sum;
        __syncthreads();
        if (t == 0) { int run = 0; for (int k = 0; k < 1024; ++k) { const int v = s_seg[k]; s_seg[k] = run; run += v; } }
        __syncthreads();
        int run = s_seg[t];
        for (int j = lo; j < hi; ++j) { off[j] = run; run += (cnt[j] + 3) & ~3; }
        __syncthreads();
    };
    scan4(gcnt, goff);
    scan4(gecnt, geoff);

    for (int i = t; i < NN; i += 1024) {
        const int m = s_meta[i], s = s_start[i];
        const int ll = m & 0xF, lr = (m >> 4) & 0xF, L = (m >> 8) & 0xF;
        for (int q = 0; q < L; ++q) {
            const int pos = goff[s + q] + atomicAdd(&gcur[s + q], 1);
            list[pos] = i | (q << 12) | (ll << 16) | (lr << 20);
            xl[pos] = (q == 0) ? i : ((q < ll) ? lch[i * KK + q - 1] : -1);
            xr[pos] = (q == 0) ? i : ((q < lr) ? rch[i * KK + q - 1] : -1);
        }
        const int ep = geoff[s + L] + atomicAdd(&gecur[s + L], 1);
        enc[ep] = i | (ll << 12) | (lr << 16);
    }
}

// ---------------------------------------------------------------------------
// Grid barrier (R4/R6/R7/R8-proven): leader-gather + XCD-fanout, flags only,
// relaxed agent scope, no fences, poll backoff. SAFE ONLY at <=256 blocks,
// 1 block/CU (TPB=1024 + 85KB LDS make 1/CU unconditional). UNCHANGED.
// ---------------------------------------------------------------------------
__device__ __forceinline__ void grid_barrier(int* ctrl, int blk, int xcd, int target) {
    __syncthreads();   // every wave: s_waitcnt vmcnt(0) before s_barrier
    if (blk == 0) {
        const int t = threadIdx.x;
        if (t < 64) {
            if (t == 0)
                __hip_atomic_store(ctrl + 0, target, __ATOMIC_RELAXED, __HIP_MEMORY_SCOPE_AGENT);
            int spin = 0;
            for (;;) {
                const int m0 = __hip_atomic_load(ctrl + t * 4 + 0, __ATOMIC_RELAXED, __HIP_MEMORY_SCOPE_AGENT);
                const int m1 = __hip_atomic_load(ctrl + t * 4 + 1, __ATOMIC_RELAXED, __HIP_MEMORY_SCOPE_AGENT);
                const int m2 = __hip_atomic_load(ctrl + t * 4 + 2, __ATOMIC_RELAXED, __HIP_MEMORY_SCOPE_AGENT);
                const int m3 = __hip_atomic_load(ctrl + t * 4 + 3, __ATOMIC_RELAXED, __HIP_MEMORY_SCOPE_AGENT);
                const bool ok = (m0 >= target) & (m1 >= target) & (m2 >= target) & (m3 >= target);
                if (__all(ok)) break;
                if (++spin > 64) __builtin_amdgcn_s_sleep(16);
                else             __builtin_amdgcn_s_sleep(1);
            }
            if (t < NXCD)
                __hip_atomic_store(ctrl + 512 + t * 16, target, __ATOMIC_RELAXED, __HIP_MEMORY_SCOPE_AGENT);
        }
    } else {
        if (threadIdx.x == 0) {
            __hip_atomic_store(ctrl + blk, target, __ATOMIC_RELAXED, __HIP_MEMORY_SCOPE_AGENT);
            int spin = 0;
            while (__hip_atomic_load(ctrl + 512 + xcd * 16, __ATOMIC_RELAXED, __HIP_MEMORY_SCOPE_AGENT) < target) {
                if (++spin > 64) __builtin_amdgcn_s_sleep(16);
                else             __builtin_amdgcn_s_sleep(1);
            }
        }
    }
    __syncthreads();
}

// Execution kernel: byte-identical to PASSING R8 (TPB=1024, launch_bounds
// (1024,1) -> 4 waves/SIMD, Occupancy 48.6%, VGPR 64 = weights served from
// hot L1, cp staged through LDS). DO NOT TOUCH this round — R9 is a pure
// scheduler experiment for clean attribution.
__global__ void __launch_bounds__(TPB, 1)
tree_lstm_kernel(const float* __restrict__ x0,
                 const float* __restrict__ Wl_ih, const float* __restrict__ Wl_hh,
                 const float* __restrict__ bl_ih, const float* __restrict__ bl_hh,
                 const float* __restrict__ Wr_ih, const float* __restrict__ Wr_hh,
                 const float* __restrict__ br_ih, const float* __restrict__ br_hh,
                 const float* __restrict__ W_enc, const float* __restrict__ b_enc,
                 float* ctx, char* ws) {
    const int tid  = threadIdx.x;
    const int wv   = tid >> 6;                 // wave index within block, 0..15
    const int wave = (blockIdx.x * TPB + tid) >> 6;  // 0..4095
    const int lane = tid & 63;
    const int u    = wave & 511;        // hidden unit owned by this wave
    const int side = (wave >> 9) & 1;   // 0 = left chain, 1 = right chain
    const int p    = (wave >> 10) & 3;  // 4-way slot split (uniform per block)
    const int egrp = (wave >> 9) & 7;   // enc: 8-way slot split
    const int xcd  = blockIdx.x & (NXCD - 1);
    const int u0b  = (blockIdx.x * 16) & 511;  // block's first unit (16 contiguous)

    int*   ctrl  = (int*)(ws + OFF_CTRL);
    int*   hdr   = (int*)(ws + OFF_HDR);
    int*   gcnt  = (int*)(ws + OFF_TCNT);
    int*   goff  = (int*)(ws + OFF_TOFF);
    int*   gecnt = (int*)(ws + OFF_ECNT);
    int*   geoff = (int*)(ws + OFF_EOFF);
    int*   list  = (int*)(ws + OFF_LIST);
    int*   xlidx = (int*)(ws + OFF_XL);
    int*   xridx = (int*)(ws + OFF_XR);
    int*   encl  = (int*)(ws + OFF_ENC);
    float* hbuf  = (float*)(ws + OFF_H);
    float* cbuf  = (float*)(ws + OFF_C);

    // double-buffered row staging (x cached->LDS, h/c bypass->reg->LDS) + pad
    __shared__ float s_x[2][8][512];
    __shared__ float s_h[2][8][512];
    __shared__ float s_c[2][8][16];
    __shared__ float s_pad[5120];   // -> ~85KB total: 1 block/CU guaranteed

    const float* Wih = side ? Wr_ih : Wl_ih;
    const float* Whh = side ? Wr_hh : Wl_hh;
    const float* bih = side ? br_ih : bl_ih;
    const float* bhh = side ? br_hh : bl_hh;

    // Wave-resident weights: 4 gate rows; lane l covers dims {4l..4l+3} and
    // {256+4l..256+4l+3} (dense 16B slices matching the LDS staging layout).
    v2f wih2[4][4], whh2[4][4];
#pragma unroll
    for (int g = 0; g < 4; ++g) {
        const size_t row = (size_t)g * HH + u;
        const float4 wa = *(const float4*)(Wih + row * DD + lane * 4);
        const float4 wb = *(const float4*)(Wih + row * DD + 256 + lane * 4);
        wih2[g][0] = (v2f){wa.x, wa.y}; wih2[g][1] = (v2f){wa.z, wa.w};
        wih2[g][2] = (v2f){wb.x, wb.y}; wih2[g][3] = (v2f){wb.z, wb.w};
        const float4 ha = *(const float4*)(Whh + row * HH + lane * 4);
        const float4 hb = *(const float4*)(Whh + row * HH + 256 + lane * 4);
        whh2[g][0] = (v2f){ha.x, ha.y}; whh2[g][1] = (v2f){ha.z, ha.w};
        whh2[g][2] = (v2f){hb.x, hb.y}; whh2[g][3] = (v2f){hb.z, hb.w};
    }
    const float bsumL = bih[(size_t)(lane & 3) * HH + u] + bhh[(size_t)(lane & 3) * HH + u];
    v2f wenc2[8];
#pragma unroll
    for (int j = 0; j < 4; ++j) {
        const float4 t = *(const float4*)(W_enc + (size_t)u * (2 * HH) + lane * 16 + j * 4);
        wenc2[j * 2 + 0] = (v2f){t.x, t.y};
        wenc2[j * 2 + 1] = (v2f){t.z, t.w};
    }
    const float bencv = b_enc[u];

    float* cb = cbuf + (size_t)side * NNHH;
    const int* xq = side ? xridx : xlidx;
    const int nt = hdr[0];
    if (nt < 0) ((volatile float*)s_pad)[tid] = 0.f;  // keep pad alive
    int bnum = 0;

    for (int tk = 0; tk < nt; ++tk) {
        const int cnt  = gcnt[tk],  off  = goff[tk];
        const int ecnt = gecnt[tk], eoff = geoff[tk];
        const int limit = off + cnt;

        // slot p owns positions {slotBase + 32c + j, j in [0,8)}
        const int slotBase = off + p * 8;
        const int nch = (limit > slotBase) ? ((limit - slotBase + 31) >> 5) : 0;

        // staging (waves 0-7 only): x rows cached glds16 -> LDS; h rows
        // ldb2 bypass -> regs; c-segment (block's 16 units, 64B) on lanes 0-7.
        // issue-early / write-late (ds_write after the next __syncthreads).
        v2f ph0, ph1, ph2, ph3, pc;
        bool pact = false;

        auto issue = [&](int buf, int chS) {
            pact = false;
            if (wv < 8) {
                const int e = chS + wv;
                if (e < limit) {
                    const int ent  = list[e];
                    const int q    = (ent >> 12) & 0xF;
                    const int xsrc = xq[e];
                    if (xsrc >= 0) {
                        const float* xrow = ((q == 0) ? x0 : ctx) + (size_t)xsrc * DD + lane * 4;
                        glds16(xrow,       &s_x[buf][wv][0]);
                        glds16(xrow + 256, &s_x[buf][wv][256]);
                        if (q > 0) {
                            pact = true;
                            const int i = ent & 0xFFF;
                            const float* hr = hbuf + (size_t)(((q & 1) ^ 1) * 2 + side) * NNHH
                                            + (size_t)i * HH + lane * 4;
                            ph0 = ldb2(hr);       ph1 = ldb2(hr + 2);
                            ph2 = ldb2(hr + 256); ph3 = ldb2(hr + 258);
                            if (lane < 8)
                                pc = ldb2(cb + (size_t)i * HH + u0b + lane * 2);
                        }
                    }
                }
            }
        };
        auto writeb = [&](int buf) {
            if (pact) {
                *(v2f*)&s_h[buf][wv][lane * 4]       = ph0;
                *(v2f*)&s_h[buf][wv][lane * 4 + 2]   = ph1;
                *(v2f*)&s_h[buf][wv][lane * 4 + 256] = ph2;
                *(v2f*)&s_h[buf][wv][lane * 4 + 258] = ph3;
                if (lane < 8)
                    *(v2f*)&s_c[buf][wv][lane * 2] = pc;
            }
        };

        if (nch > 0) { issue(0, slotBase); writeb(0); }
        for (int c = 0; c < nch; ++c) {
            __syncthreads();                    // buf[c&1] staged (all waves)
            const int chS = slotBase + (c << 5);
            if (c + 1 < nch) issue((c + 1) & 1, chS + 32);
            const int bb = c & 1;

            const int4 eA = *(const int4*)(list + chS);
            const int4 eB = *(const int4*)(list + chS + 4);
            const int4 cA = *(const int4*)(xq + chS);
            const int4 cB = *(const int4*)(xq + chS + 4);
            const int ei[8] = {eA.x, eA.y, eA.z, eA.w, eB.x, eB.y, eB.z, eB.w};
            const int ci[8] = {cA.x, cA.y, cA.z, cA.w, cB.x, cB.y, cB.z, cB.w};
            bool act[8];
#pragma unroll
            for (int j = 0; j < 8; ++j)
                act[j] = (chS + j < limit) && (ci[j] >= 0);

#pragma unroll
            for (int j = 0; j < 8; ++j) {
                if (!act[j]) continue;
                const int ent = ei[j];
                const int i   = ent & 0xFFF;
                const int qj  = (ent >> 12) & 0xF;
                const float cpj = (qj > 0) ? s_c[bb][j][wv] : 0.f;  // LDS broadcast
                const float4 xa = *(const float4*)&s_x[bb][j][lane * 4];
                const float4 xc = *(const float4*)&s_x[bb][j][lane * 4 + 256];
                v2f xv0 = (v2f){xa.x, xa.y}, xv1 = (v2f){xa.z, xa.w};
                v2f xv2 = (v2f){xc.x, xc.y}, xv3 = (v2f){xc.z, xc.w};
                v2f A0 = wih2[0][0] * xv0 + wih2[0][1] * xv1 + wih2[0][2] * xv2 + wih2[0][3] * xv3;
                v2f A1 = wih2[1][0] * xv0 + wih2[1][1] * xv1 + wih2[1][2] * xv2 + wih2[1][3] * xv3;
                v2f A2 = wih2[2][0] * xv0 + wih2[2][1] * xv1 + wih2[2][2] * xv2 + wih2[2][3] * xv3;
                v2f A3 = wih2[3][0] * xv0 + wih2[3][1] * xv1 + wih2[3][2] * xv2 + wih2[3][3] * xv3;
                if (qj > 0) {
                    const float4 ha = *(const float4*)&s_h[bb][j][lane * 4];
                    const float4 hc = *(const float4*)&s_h[bb][j][lane * 4 + 256];
                    v2f hv0 = (v2f){ha.x, ha.y}, hv1 = (v2f){ha.z, ha.w};
                    v2f hv2 = (v2f){hc.x, hc.y}, hv3 = (v2f){hc.z, hc.w};
                    A0 += whh2[0][0] * hv0 + whh2[0][1] * hv1 + whh2[0][2] * hv2 + whh2[0][3] * hv3;
                    A1 += whh2[1][0] * hv0 + whh2[1][1] * hv1 + whh2[1][2] * hv2 + whh2[1][3] * hv3;
                    A2 += whh2[2][0] * hv0 + whh2[2][1] * hv1 + whh2[2][2] * hv2 + whh2[2][3] * hv3;
                    A3 += whh2[3][0] * hv0 + whh2[3][1] * hv1 + whh2[3][2] * hv2 + whh2[3][3] * hv3;
                }
                float a0 = A0[0] + A0[1], a1 = A1[0] + A1[1];
                float a2 = A2[0] + A2[1], a3 = A3[0] + A3[1];
                // merge butterfly: lane l ends holding gate (l&3)'s sum
                float v01, v23, v;
                {
                    const bool hi = lane & 1;
                    float keep = hi ? a1 : a0, send = hi ? a0 : a1;
                    v01 = keep + __shfl_xor(send, 1, 64);
                    keep = hi ? a3 : a2; send = hi ? a2 : a3;
                    v23 = keep + __shfl_xor(send, 1, 64);
                }
                {
                    const bool hi = lane & 2;
                    const float keep = hi ? v23 : v01, send = hi ? v01 : v23;
                    v = keep + __shfl_xor(send, 2, 64);
                }
                v += __shfl_xor(v, 4, 64);
                v += __shfl_xor(v, 8, 64);
                v += __shfl_xor(v, 16, 64);
                v += __shfl_xor(v, 32, 64);
                // wave-parallel nonlinearities: sigm(x)=(tanh(x/2)+1)/2
                const float gate = v + bsumL;
                const bool  isG  = (lane & 3) == 2;
                const float th   = fast_tanh2x(isG ? (gate + gate) : gate);
                const float tl   = isG ? th : 0.5f * (th + 1.0f);
                const float ti = __shfl(tl, 0, 64);
                const float tf = __shfl(tl, 1, 64);
                const float tg = __shfl(tl, 2, 64);
                const float to = __shfl(tl, 3, 64);
                const float cn = tf * cpj + ti * tg;
                const float hn = to * fast_tanh2x(cn + cn);
                if (lane == 0) {
                    coh_store(cb + (size_t)i * HH + u, cn);
                    coh_store(hbuf + (size_t)((qj & 1) * 2 + side) * NNHH + (size_t)i * HH + u, hn);
                }
            }
            if (c + 1 < nch) writeb((c + 1) & 1);   // waits loads, LDS write
        }

        // enc for nodes whose last substep ran at tick tk-1 (h MALL-visible)
        if (ecnt > 0) {
            const int lhalf = lane >> 5;
            const int col   = (lane * 16) & 511;
            const int elim  = eoff + ecnt;
            for (int slot = eoff + egrp; slot < elim; slot += 8) {
                const int e   = encl[slot];
                const int i   = e & 0xFFF;
                const int len = (e >> (12 + 4 * lhalf)) & 0xF;
                const float* hv = hbuf + (size_t)(((len - 1) & 1) * 2 + lhalf) * NNHH
                                + (size_t)i * HH + col;
                v2f acc2 = {0.f, 0.f};
#pragma unroll
                for (int k = 0; k < 8; ++k)
                    acc2 += wenc2[k] * ldb2(hv + k * 2);
                float acc = acc2[0] + acc2[1];
#pragma unroll
                for (int m = 1; m < 64; m <<= 1) acc += __shfl_xor(acc, m, 64);
                if (lane == 0)
                    coh_store(&ctx[(size_t)i * DD + u], fast_tanh2x(2.0f * (acc + bencv)));
            }
        }
        grid_barrier(ctrl, blockIdx.x, xcd, ++bnum);
    }
}

extern "C" void kernel_launch(void* const* d_in, const int* in_sizes, int n_in,
                              void* d_out, int out_size, void* d_ws, size_t ws_size,
                              hipStream_t stream) {
    hipMemsetAsync(d_ws, 0, WS_ZERO_BYTES, stream);
    sched_kernel<<<dim3(1), dim3(1024), 0, stream>>>(
        (const int*)d_in[11], (const int*)d_in[12], (char*)d_ws);
    tree_lstm_kernel<<<dim3(NB), dim3(TPB), 0, stream>>>(
        (const float*)d_in[0],
        (const float*)d_in[1], (const float*)d_in[2],
        (const float*)d_in[3], (const float*)d_in[4],
        (const float*)d_in[5], (const float*)d_in[6],
        (const float*)d_in[7], (const float*)d_in[8],
        (const float*)d_in[9], (const float*)d_in[10],
        (float*)d_out, (char*)d_ws);
}